// Round 2
// baseline (439.971 us; speedup 1.0000x reference)
//
#include <hip/hip_runtime.h>
#include <hip/hip_bf16.h>

// ---------------------------------------------------------------------------
// FFT butterfly attention. delta = x_a^T P (x_a - x_b), P = scale*Wq*Wk^T
// (bf16, MFMA prep). w0 = sigmoid(delta); v' = mix(va, vb).
//
// Structure = the verified 267us kernel (G = Xa @ P staged through gbuf,
// split-wave dot, 2 barriers/stage), plus three counter-driven fixes:
//  1. PT stored FRAGMENT-MAJOR by prep (PTf): butterfly's 8 B-frag loads are
//     fully coalesced 1KB wave reads (was 16-segment 256B-strided gathers).
//  2. bfr register prefetch: stage u+1's PT frags issued right after stage
//     u's MFMAs consume bfr -> latency hidden under gbuf+dot+mix+barriers.
//  3. gbuf in bf16 (64 x 132 ushorts = 16.9KB): LDS 68.9K -> 51.9K
//     -> 3 blocks/CU (launch_bounds(512,6)). Dot read stays conflict-free
//     (same-row uint2, 2-way=free); writes <=2-way.
//
// v register layout (pair-local): at stage u, lane L holds BOTH partners:
//   vlo = row ((L>>u)<<(u+1)) | (L & (2^u-1)),  vhi = vlo + 2^u
// -> mix is pure in-thread VALU; between stages each lane exchanges one value
// with lane L^2^u (DPP quad_perm / ds_swizzle xor / ds_bpermute), fused in.
// ---------------------------------------------------------------------------

typedef __bf16 bf16x8 __attribute__((ext_vector_type(8)));
typedef float  f32x4  __attribute__((ext_vector_type(4)));

#define XSTR 136                    // bf16 elems per xb row (128 + 8 pad; 272B = 16B-aligned rows)
#define GH_STR 132                  // bf16 elems per gbuf row (264B rows, 8B-aligned)
#define XB_BYTES  (128 * XSTR * 2)  // 34816
#define GB_OFF    XB_BYTES
#define GB_BYTES  (64 * GH_STR * 2) // 16896
#define WT_OFF    (GB_OFF + GB_BYTES)
#define LDS_MAIN  (WT_OFF + 64 * 4) // 51968 -> 3 WGs/CU
#define PREP_LDS  (2 * XB_BYTES)    // 69632

__device__ __forceinline__ float ubits(unsigned int u) {
    union { unsigned int u; float f; } v; v.u = u; return v.f;
}
__device__ __forceinline__ unsigned short f2bf(float f) {
    union { float f; unsigned int u; } v; v.f = f;
    unsigned int u = v.u;
    return (unsigned short)((u + 0x7fffu + ((u >> 16) & 1u)) >> 16);
}

#define DPP_MOV_F(x, ctrl) \
    __int_as_float(__builtin_amdgcn_update_dpp(0, __float_as_int(x), (ctrl), 0xF, 0xF, true))
#define DPP_ADD_F(s, ctrl) s += DPP_MOV_F(s, ctrl)

// cross-lane xor exchange with lane ^ (1<<u); u is compile-time-folded
__device__ __forceinline__ float xlane_u(float x, int u, int lane) {
    if (u == 0) return DPP_MOV_F(x, 0xB1);   // quad_perm xor1
    if (u == 1) return DPP_MOV_F(x, 0x4E);   // quad_perm xor2
    if (u == 2) return __int_as_float(__builtin_amdgcn_ds_swizzle(__float_as_int(x), 0x101F)); // xor4
    if (u == 3) return __int_as_float(__builtin_amdgcn_ds_swizzle(__float_as_int(x), 0x201F)); // xor8
    if (u == 4) return __int_as_float(__builtin_amdgcn_ds_swizzle(__float_as_int(x), 0x401F)); // xor16
    return __int_as_float(__builtin_amdgcn_ds_bpermute((lane ^ 32) << 2, __float_as_int(x))); // xor32
}

// ---------------- prep: PTf = fragment-major P^T -----------------------------
// Element (n,k) of PT (n = G-col, k = contraction dim) lives at
//   fi = ((cg*2+ct)*4 + kk)*64 + quad*16 + lane15 , elem e
// with cg=n>>5, ct=(n>>4)&1, lane15=n&15, kk=k>>5, quad=(k>>3)&3, e=k&7,
// so butterfly's bfr[ct*4+kk] load = Pf[((cg*2+ct)*4+kk)*64 + lane]: 1KB coalesced.
__global__ __launch_bounds__(512)
void prep_kernel(const float* __restrict__ qkw, unsigned short* __restrict__ PT) {
    extern __shared__ char smem[];
    unsigned short* wkb = (unsigned short*)smem;              // A: Wk rows (n)
    unsigned short* wqb = (unsigned short*)(smem + XB_BYTES); // B: Wq rows (k)
    const int s = blockIdx.x;
    const float* Wq = qkw + (size_t)s * 32768;
    const float* Wk = Wq + 16384;
    const int tid = threadIdx.x;
    const int rl = tid >> 5, c4 = tid & 31;
#pragma unroll
    for (int j = 0; j < 8; ++j) {
        int r = j * 16 + rl;
        float4 vq = ((const float4*)Wq)[r * 32 + c4];
        float4 vk = ((const float4*)Wk)[r * 32 + c4];
        ushort4 uq; uq.x = f2bf(vq.x); uq.y = f2bf(vq.y); uq.z = f2bf(vq.z); uq.w = f2bf(vq.w);
        ushort4 uk; uk.x = f2bf(vk.x); uk.y = f2bf(vk.y); uk.z = f2bf(vk.z); uk.w = f2bf(vk.w);
        *(ushort4*)(wqb + r * XSTR + c4 * 4) = uq;
        *(ushort4*)(wkb + r * XSTR + c4 * 4) = uk;
    }
    __syncthreads();
    const int lane = tid & 63, w = tid >> 6;
    const int lane15 = lane & 15, quad = lane >> 4;
    f32x4 acc[8] = {};
#pragma unroll
    for (int kk = 0; kk < 4; ++kk) {
        bf16x8 a = *(const bf16x8*)(wkb + (w * 16 + lane15) * XSTR + kk * 32 + quad * 8);
#pragma unroll
        for (int ct = 0; ct < 8; ++ct) {
            bf16x8 b = *(const bf16x8*)(wqb + (ct * 16 + lane15) * XSTR + kk * 32 + quad * 8);
            acc[ct] = __builtin_amdgcn_mfma_f32_16x16x32_bf16(a, b, acc[ct], 0, 0, 0);
        }
    }
    // acc[ct][r] = PT[n][k], n = w*16 + quad*4 + r, k = ct*16 + lane15
    unsigned short* dst = PT + s * 16384;
#pragma unroll
    for (int ct = 0; ct < 8; ++ct) {
        const int kkf = ct >> 1;
        const int qf  = (ct & 1) * 2 + (lane15 >> 3);
        const int e   = lane15 & 7;
#pragma unroll
        for (int r = 0; r < 4; ++r) {
            int fi = (w * 4 + kkf) * 64 + qf * 16 + quad * 4 + r;
            dst[fi * 8 + e] = f2bf(acc[ct][r] * 0.17677669529663687f);
        }
    }
}

// ---------------- fused butterfly stages ------------------------------------
template<int NS>
__global__ __launch_bounds__(512, 6)
void butterfly_kernel(const float* __restrict__ xsrc,
                      const float* __restrict__ vsrc,
                      float* __restrict__ vdst,
                      const unsigned short* __restrict__ PT,
                      int s0, int base_mul, int h_off, int rstride)
{
    extern __shared__ char smem[];
    unsigned short* xb   = (unsigned short*)smem;
    unsigned short* gbuf = (unsigned short*)(smem + GB_OFF);
    float*          wt   = (float*)(smem + WT_OFF);

    const int tid  = threadIdx.x;
    const int b    = blockIdx.x >> 6;
    const int sub  = blockIdx.x & 63;
    const int base = b * 8192 + sub * base_mul;

    // ---- stage x -> xb (bf16), coalesced ----
    {
        const int rl = tid >> 5, c4 = tid & 31;
#pragma unroll
        for (int j = 0; j < 8; ++j) {
            int i  = j * 16 + rl;
            int gp = base + (i >> 6) * h_off + (i & 63) * rstride;
            float4 val = ((const float4*)xsrc)[gp * 32 + c4];
            ushort4 us; us.x = f2bf(val.x); us.y = f2bf(val.y);
            us.z = f2bf(val.z); us.w = f2bf(val.w);
            *(ushort4*)(xb + i * XSTR + c4 * 4) = us;
        }
    }

    const int lane = tid & 63, w = tid >> 6;
    const int lane15 = lane & 15, quad = lane >> 4;
    const int rg = w >> 2, cg = w & 3;

    // ---- v into registers, pair-local for stage 0: rows (2L, 2L+1) ----
    float vlo[16], vhi[16];
    {
        int r0 = 2 * lane, r1 = r0 + 1;
        int gp0 = base + (r0 >> 6) * h_off + (r0 & 63) * rstride;
        int gp1 = base + (r1 >> 6) * h_off + (r1 & 63) * rstride;
        const float* p0 = vsrc + (size_t)gp0 * 128 + w * 16;
        const float* p1 = vsrc + (size_t)gp1 * 128 + w * 16;
#pragma unroll
        for (int j = 0; j < 4; ++j) {
            float4 a = ((const float4*)p0)[j];
            float4 c = ((const float4*)p1)[j];
            vlo[4*j] = a.x; vlo[4*j+1] = a.y; vlo[4*j+2] = a.z; vlo[4*j+3] = a.w;
            vhi[4*j] = c.x; vhi[4*j+1] = c.y; vhi[4*j+2] = c.z; vhi[4*j+3] = c.w;
        }
    }

    // ---- prefetch stage-0 PT frags (coalesced 1KB loads) ----
    uint4 bfr[8];
    const uint4* Pfbase = (const uint4*)PT;   // stage s at offset s*2048 uint4s
    {
        const uint4* Pf = Pfbase + (size_t)s0 * 2048;
#pragma unroll
        for (int ct = 0; ct < 2; ++ct)
#pragma unroll
            for (int kk = 0; kk < 4; ++kk)
                bfr[ct * 4 + kk] = Pf[((cg * 2 + ct) * 4 + kk) * 64 + lane];
    }
    __syncthreads();   // xb ready

#pragma unroll
    for (int u = 0; u < NS; ++u) {
        const int t   = 1 << u;
        const int tm1 = t - 1;

        // ---- GEMM: G[64x128] = Xa @ P; B-frags already in registers ----
        {
            const int m0 = rg * 32 + lane15, m1 = m0 + 16;
            const int ar0 = ((m0 & ~tm1) << 1) | (m0 & tm1);
            const int ar1 = ((m1 & ~tm1) << 1) | (m1 & tm1);
            f32x4 acc[2][2] = {};
#pragma unroll
            for (int kk = 0; kk < 4; ++kk) {
                bf16x8 a0 = *(const bf16x8*)(xb + ar0 * XSTR + kk * 32 + quad * 8);
                bf16x8 a1 = *(const bf16x8*)(xb + ar1 * XSTR + kk * 32 + quad * 8);
#pragma unroll
                for (int ct = 0; ct < 2; ++ct) {
                    union { uint4 u; bf16x8 b; } cv; cv.u = bfr[ct * 4 + kk];
                    acc[0][ct] = __builtin_amdgcn_mfma_f32_16x16x32_bf16(a0, cv.b, acc[0][ct], 0, 0, 0);
                    acc[1][ct] = __builtin_amdgcn_mfma_f32_16x16x32_bf16(a1, cv.b, acc[1][ct], 0, 0, 0);
                }
            }

            // ---- prefetch next stage's PT frags while MFMAs/dot/mix run ----
            if (u + 1 < NS) {
                const uint4* Pf = Pfbase + (size_t)(s0 + u + 1) * 2048;
#pragma unroll
                for (int ct = 0; ct < 2; ++ct)
#pragma unroll
                    for (int kk = 0; kk < 4; ++kk)
                        bfr[ct * 4 + kk] = Pf[((cg * 2 + ct) * 4 + kk) * 64 + lane];
            }

#pragma unroll
            for (int rt = 0; rt < 2; ++rt)
#pragma unroll
                for (int ct = 0; ct < 2; ++ct)
#pragma unroll
                    for (int r = 0; r < 4; ++r)
                        gbuf[(rg * 32 + rt * 16 + quad * 4 + r) * GH_STR + cg * 32 + ct * 16 + lane15]
                            = f2bf(acc[rt][ct][r]);
        }
        __syncthreads();   // S4: gbuf ready (also fences wt reads of prev stage)

        // ---- dot: 2 pairs per iter (32 lanes x 4 cols each) + DPP reduce ----
        {
            const int half = lane >> 5, l32 = lane & 31, c0 = l32 * 4;
#pragma unroll
            for (int it = 0; it < 4; ++it) {
                int p  = w * 8 + it * 2 + half;
                int ar = ((p & ~tm1) << 1) | (p & tm1);
                int br = ar + t;
                uint2 ua = *(const uint2*)(xb + ar * XSTR + c0);
                uint2 ub = *(const uint2*)(xb + br * XSTR + c0);
                uint2 gg = *(const uint2*)(gbuf + p * GH_STR + c0);
                float a0 = ubits(ua.x << 16), a1 = ubits(ua.x & 0xffff0000u);
                float a2 = ubits(ua.y << 16), a3 = ubits(ua.y & 0xffff0000u);
                float b0 = ubits(ub.x << 16), b1 = ubits(ub.x & 0xffff0000u);
                float b2 = ubits(ub.y << 16), b3 = ubits(ub.y & 0xffff0000u);
                float g0 = ubits(gg.x << 16), g1 = ubits(gg.x & 0xffff0000u);
                float g2 = ubits(gg.y << 16), g3 = ubits(gg.y & 0xffff0000u);
                float sm = g0 * (a0 - b0) + g1 * (a1 - b1)
                         + g2 * (a2 - b2) + g3 * (a3 - b3);
                DPP_ADD_F(sm, 0x111);  // row_shr:1
                DPP_ADD_F(sm, 0x112);  // row_shr:2
                DPP_ADD_F(sm, 0x114);  // row_shr:4
                DPP_ADD_F(sm, 0x118);  // row_shr:8
                DPP_ADD_F(sm, 0x142);  // row_bcast:15 -> lane31 / lane63 hold sums
                if (l32 == 31) wt[p] = 1.0f / (1.0f + __expf(-sm));
            }
        }
        __syncthreads();   // S5: weights ready

        // ---- mix (in-thread) + fused pair exchange for next stage ----
        {
            const float w0 = wt[lane];
            if (u < NS - 1) {
                const bool isE = ((lane >> u) & 1) == 0;
                const float wk = isE ? w0 : 1.0f - w0;
#pragma unroll
                for (int j = 0; j < 16; ++j) {
                    float a = vlo[j], c = vhi[j];
                    float s    = a + c;
                    float keep = c + wk * (a - c);   // E: out_a ; O: out_b
                    float send = s - keep;           // E: out_b ; O: out_a
                    float ex   = xlane_u(send, u, lane);
                    vlo[j] = isE ? keep : ex;
                    vhi[j] = isE ? ex : keep;
                }
            } else {
                const float w1 = 1.0f - w0;
#pragma unroll
                for (int j = 0; j < 16; ++j) {
                    float a = vlo[j], c = vhi[j];
                    float oa = w0 * a + w1 * c;
                    vlo[j] = oa;
                    vhi[j] = a + c - oa;
                }
            }
        }
    }

    // ---- store v registers -> vdst (layout of final stage NS-1) ----
    {
        const int FU = NS - 1;
        int r0 = ((lane >> FU) << (FU + 1)) | (lane & ((1 << FU) - 1));
        int r1 = r0 + (1 << FU);
        int gp0 = base + (r0 >> 6) * h_off + (r0 & 63) * rstride;
        int gp1 = base + (r1 >> 6) * h_off + (r1 & 63) * rstride;
        float* p0 = vdst + (size_t)gp0 * 128 + w * 16;
        float* p1 = vdst + (size_t)gp1 * 128 + w * 16;
#pragma unroll
        for (int j = 0; j < 4; ++j) {
            float4 a; a.x = vlo[4*j]; a.y = vlo[4*j+1]; a.z = vlo[4*j+2]; a.w = vlo[4*j+3];
            float4 c; c.x = vhi[4*j]; c.y = vhi[4*j+1]; c.z = vhi[4*j+2]; c.w = vhi[4*j+3];
            ((float4*)p0)[j] = a;
            ((float4*)p1)[j] = c;
        }
    }
}

extern "C" void kernel_launch(void* const* d_in, const int* in_sizes, int n_in,
                              void* d_out, int out_size, void* d_ws, size_t ws_size,
                              hipStream_t stream) {
    const float* x   = (const float*)d_in[0];
    const float* qkw = (const float*)d_in[1];
    float* out = (float*)d_out;
    unsigned short* PT = (unsigned short*)d_ws;   // 13*16384 bf16 = 416 KB

    (void)hipFuncSetAttribute((const void*)prep_kernel,
                              hipFuncAttributeMaxDynamicSharedMemorySize, PREP_LDS);
    (void)hipFuncSetAttribute((const void*)butterfly_kernel<7>,
                              hipFuncAttributeMaxDynamicSharedMemorySize, LDS_MAIN);
    (void)hipFuncSetAttribute((const void*)butterfly_kernel<6>,
                              hipFuncAttributeMaxDynamicSharedMemorySize, LDS_MAIN);

    prep_kernel<<<13, 512, PREP_LDS, stream>>>(qkw, PT);

    // stages 0..6: contiguous 128-position blocks; v init = x
    butterfly_kernel<7><<<1024, 512, LDS_MAIN, stream>>>(
        x, x, out, PT, /*s0=*/0, /*base_mul=*/128, /*h_off=*/64, /*rstride=*/1);

    // stages 7..12: 2 lo x 64 hi (stride 128); in-place on d_out
    butterfly_kernel<6><<<1024, 512, LDS_MAIN, stream>>>(
        x, out, out, PT, /*s0=*/7, /*base_mul=*/2, /*h_off=*/1, /*rstride=*/128);
}

// Round 3
// 248.812 us; speedup vs baseline: 1.7683x; 1.7683x over previous
//
#include <hip/hip_runtime.h>
#include <hip/hip_bf16.h>

// ---------------------------------------------------------------------------
// FFT butterfly attention. delta = x_a^T P (x_a - x_b), P = scale*Wq*Wk^T
// (bf16, MFMA prep). w0 = sigmoid(delta); v' = mix(va, vb).
//
// Structure = the verified 97us/launch round-0 kernel (G = Xa @ P staged
// through gbuf, split-wave dot, 2 barriers/stage), with two fixes that were
// correctness-verified in round 2 but poisoned there by register spills:
//  1. PT stored FRAGMENT-MAJOR by prep (PTf): butterfly's 8 B-frag loads are
//     fully coalesced 1KB wave reads (was 16-segment 256B-strided gathers).
//     bfr is TRANSIENT inside the GEMM scope (round-0 style) -> no spills.
//  2. gbuf in bf16 (64 x 132 ushorts = 16.9KB): LDS 68.9K -> 51.9K
//     -> 3 WGs/CU from the LDS limit (VGPR ~60 allows 8 waves/SIMD).
//     launch_bounds(512,4) = round-0's proven register discipline.
//
// v register layout (pair-local): at stage u, lane L holds BOTH partners:
//   vlo = row ((L>>u)<<(u+1)) | (L & (2^u-1)),  vhi = vlo + 2^u
// -> mix is pure in-thread VALU; between stages each lane exchanges one value
// with lane L^2^u (DPP quad_perm / ds_swizzle xor / ds_bpermute), fused in.
// ---------------------------------------------------------------------------

typedef __bf16 bf16x8 __attribute__((ext_vector_type(8)));
typedef float  f32x4  __attribute__((ext_vector_type(4)));

#define XSTR 136                    // bf16 elems per xb row (128 + 8 pad; 272B rows)
#define GH_STR 132                  // bf16 elems per gbuf row (264B rows)
#define XB_BYTES  (128 * XSTR * 2)  // 34816
#define GB_OFF    XB_BYTES
#define GB_BYTES  (64 * GH_STR * 2) // 16896
#define WT_OFF    (GB_OFF + GB_BYTES)
#define LDS_MAIN  (WT_OFF + 64 * 4) // 51968 -> 3 WGs/CU
#define PREP_LDS  (2 * XB_BYTES)    // 69632

__device__ __forceinline__ float ubits(unsigned int u) {
    union { unsigned int u; float f; } v; v.u = u; return v.f;
}
__device__ __forceinline__ unsigned short f2bf(float f) {
    union { float f; unsigned int u; } v; v.f = f;
    unsigned int u = v.u;
    return (unsigned short)((u + 0x7fffu + ((u >> 16) & 1u)) >> 16);
}

#define DPP_MOV_F(x, ctrl) \
    __int_as_float(__builtin_amdgcn_update_dpp(0, __float_as_int(x), (ctrl), 0xF, 0xF, true))
#define DPP_ADD_F(s, ctrl) s += DPP_MOV_F(s, ctrl)

// cross-lane xor exchange with lane ^ (1<<u); u is compile-time-folded
__device__ __forceinline__ float xlane_u(float x, int u, int lane) {
    if (u == 0) return DPP_MOV_F(x, 0xB1);   // quad_perm xor1
    if (u == 1) return DPP_MOV_F(x, 0x4E);   // quad_perm xor2
    if (u == 2) return __int_as_float(__builtin_amdgcn_ds_swizzle(__float_as_int(x), 0x101F)); // xor4
    if (u == 3) return __int_as_float(__builtin_amdgcn_ds_swizzle(__float_as_int(x), 0x201F)); // xor8
    if (u == 4) return __int_as_float(__builtin_amdgcn_ds_swizzle(__float_as_int(x), 0x401F)); // xor16
    return __int_as_float(__builtin_amdgcn_ds_bpermute((lane ^ 32) << 2, __float_as_int(x))); // xor32
}

// ---------------- prep: PTf = fragment-major P^T -----------------------------
// Element (n,k) of PT (n = G-col, k = contraction dim) lives at
//   fi = ((cg*2+ct)*4 + kk)*64 + quad*16 + lane15 , elem e
// with cg=n>>5, ct=(n>>4)&1, lane15=n&15, kk=k>>5, quad=(k>>3)&3, e=k&7,
// so butterfly's bfr[ct*4+kk] load = Pf[((cg*2+ct)*4+kk)*64 + lane]: 1KB coalesced.
__global__ __launch_bounds__(512)
void prep_kernel(const float* __restrict__ qkw, unsigned short* __restrict__ PT) {
    extern __shared__ char smem[];
    unsigned short* wkb = (unsigned short*)smem;              // A: Wk rows (n)
    unsigned short* wqb = (unsigned short*)(smem + XB_BYTES); // B: Wq rows (k)
    const int s = blockIdx.x;
    const float* Wq = qkw + (size_t)s * 32768;
    const float* Wk = Wq + 16384;
    const int tid = threadIdx.x;
    const int rl = tid >> 5, c4 = tid & 31;
#pragma unroll
    for (int j = 0; j < 8; ++j) {
        int r = j * 16 + rl;
        float4 vq = ((const float4*)Wq)[r * 32 + c4];
        float4 vk = ((const float4*)Wk)[r * 32 + c4];
        ushort4 uq; uq.x = f2bf(vq.x); uq.y = f2bf(vq.y); uq.z = f2bf(vq.z); uq.w = f2bf(vq.w);
        ushort4 uk; uk.x = f2bf(vk.x); uk.y = f2bf(vk.y); uk.z = f2bf(vk.z); uk.w = f2bf(vk.w);
        *(ushort4*)(wqb + r * XSTR + c4 * 4) = uq;
        *(ushort4*)(wkb + r * XSTR + c4 * 4) = uk;
    }
    __syncthreads();
    const int lane = tid & 63, w = tid >> 6;
    const int lane15 = lane & 15, quad = lane >> 4;
    f32x4 acc[8] = {};
#pragma unroll
    for (int kk = 0; kk < 4; ++kk) {
        bf16x8 a = *(const bf16x8*)(wkb + (w * 16 + lane15) * XSTR + kk * 32 + quad * 8);
#pragma unroll
        for (int ct = 0; ct < 8; ++ct) {
            bf16x8 b = *(const bf16x8*)(wqb + (ct * 16 + lane15) * XSTR + kk * 32 + quad * 8);
            acc[ct] = __builtin_amdgcn_mfma_f32_16x16x32_bf16(a, b, acc[ct], 0, 0, 0);
        }
    }
    // acc[ct][r] = PT[n][k], n = w*16 + quad*4 + r, k = ct*16 + lane15
    unsigned short* dst = PT + s * 16384;
#pragma unroll
    for (int ct = 0; ct < 8; ++ct) {
        const int kkf = ct >> 1;
        const int qf  = (ct & 1) * 2 + (lane15 >> 3);
        const int e   = lane15 & 7;
#pragma unroll
        for (int r = 0; r < 4; ++r) {
            int fi = (w * 4 + kkf) * 64 + qf * 16 + quad * 4 + r;
            dst[fi * 8 + e] = f2bf(acc[ct][r] * 0.17677669529663687f);
        }
    }
}

// ---------------- fused butterfly stages ------------------------------------
template<int NS>
__global__ __launch_bounds__(512, 4)
void butterfly_kernel(const float* __restrict__ xsrc,
                      const float* __restrict__ vsrc,
                      float* __restrict__ vdst,
                      const unsigned short* __restrict__ PT,
                      int s0, int base_mul, int h_off, int rstride)
{
    extern __shared__ char smem[];
    unsigned short* xb   = (unsigned short*)smem;
    unsigned short* gbuf = (unsigned short*)(smem + GB_OFF);
    float*          wt   = (float*)(smem + WT_OFF);

    const int tid  = threadIdx.x;
    const int b    = blockIdx.x >> 6;
    const int sub  = blockIdx.x & 63;
    const int base = b * 8192 + sub * base_mul;

    // ---- stage x -> xb (bf16), coalesced ----
    {
        const int rl = tid >> 5, c4 = tid & 31;
#pragma unroll
        for (int j = 0; j < 8; ++j) {
            int i  = j * 16 + rl;
            int gp = base + (i >> 6) * h_off + (i & 63) * rstride;
            float4 val = ((const float4*)xsrc)[gp * 32 + c4];
            ushort4 us; us.x = f2bf(val.x); us.y = f2bf(val.y);
            us.z = f2bf(val.z); us.w = f2bf(val.w);
            *(ushort4*)(xb + i * XSTR + c4 * 4) = us;
        }
    }

    const int lane = tid & 63, w = tid >> 6;
    const int lane15 = lane & 15, quad = lane >> 4;
    const int rg = w >> 2, cg = w & 3;

    // ---- v into registers, pair-local for stage 0: rows (2L, 2L+1) ----
    float vlo[16], vhi[16];
    {
        int r0 = 2 * lane, r1 = r0 + 1;
        int gp0 = base + (r0 >> 6) * h_off + (r0 & 63) * rstride;
        int gp1 = base + (r1 >> 6) * h_off + (r1 & 63) * rstride;
        const float* p0 = vsrc + (size_t)gp0 * 128 + w * 16;
        const float* p1 = vsrc + (size_t)gp1 * 128 + w * 16;
#pragma unroll
        for (int j = 0; j < 4; ++j) {
            float4 a = ((const float4*)p0)[j];
            float4 c = ((const float4*)p1)[j];
            vlo[4*j] = a.x; vlo[4*j+1] = a.y; vlo[4*j+2] = a.z; vlo[4*j+3] = a.w;
            vhi[4*j] = c.x; vhi[4*j+1] = c.y; vhi[4*j+2] = c.z; vhi[4*j+3] = c.w;
        }
    }
    __syncthreads();   // xb ready

#pragma unroll
    for (int u = 0; u < NS; ++u) {
        const int t   = 1 << u;
        const int tm1 = t - 1;

        // ---- GEMM: G[64x128] = Xa @ P; B-frags coalesced from PTf ----
        {
            const uint4* Pf = (const uint4*)PT + (size_t)(s0 + u) * 2048;
            uint4 bfr[8];
#pragma unroll
            for (int ct = 0; ct < 2; ++ct)
#pragma unroll
                for (int kk = 0; kk < 4; ++kk)
                    bfr[ct * 4 + kk] = Pf[((cg * 2 + ct) * 4 + kk) * 64 + lane];

            const int m0 = rg * 32 + lane15, m1 = m0 + 16;
            const int ar0 = ((m0 & ~tm1) << 1) | (m0 & tm1);
            const int ar1 = ((m1 & ~tm1) << 1) | (m1 & tm1);
            f32x4 acc[2][2] = {};
#pragma unroll
            for (int kk = 0; kk < 4; ++kk) {
                bf16x8 a0 = *(const bf16x8*)(xb + ar0 * XSTR + kk * 32 + quad * 8);
                bf16x8 a1 = *(const bf16x8*)(xb + ar1 * XSTR + kk * 32 + quad * 8);
#pragma unroll
                for (int ct = 0; ct < 2; ++ct) {
                    union { uint4 u; bf16x8 b; } cv; cv.u = bfr[ct * 4 + kk];
                    acc[0][ct] = __builtin_amdgcn_mfma_f32_16x16x32_bf16(a0, cv.b, acc[0][ct], 0, 0, 0);
                    acc[1][ct] = __builtin_amdgcn_mfma_f32_16x16x32_bf16(a1, cv.b, acc[1][ct], 0, 0, 0);
                }
            }
#pragma unroll
            for (int rt = 0; rt < 2; ++rt)
#pragma unroll
                for (int ct = 0; ct < 2; ++ct)
#pragma unroll
                    for (int r = 0; r < 4; ++r)
                        gbuf[(rg * 32 + rt * 16 + quad * 4 + r) * GH_STR + cg * 32 + ct * 16 + lane15]
                            = f2bf(acc[rt][ct][r]);
        }
        __syncthreads();   // S4: gbuf ready (also fences wt reads of prev stage)

        // ---- dot: 2 pairs per iter (32 lanes x 4 cols each) + DPP reduce ----
        {
            const int half = lane >> 5, l32 = lane & 31, c0 = l32 * 4;
#pragma unroll
            for (int it = 0; it < 4; ++it) {
                int p  = w * 8 + it * 2 + half;
                int ar = ((p & ~tm1) << 1) | (p & tm1);
                int br = ar + t;
                uint2 ua = *(const uint2*)(xb + ar * XSTR + c0);
                uint2 ub = *(const uint2*)(xb + br * XSTR + c0);
                uint2 gg = *(const uint2*)(gbuf + p * GH_STR + c0);
                float a0 = ubits(ua.x << 16), a1 = ubits(ua.x & 0xffff0000u);
                float a2 = ubits(ua.y << 16), a3 = ubits(ua.y & 0xffff0000u);
                float b0 = ubits(ub.x << 16), b1 = ubits(ub.x & 0xffff0000u);
                float b2 = ubits(ub.y << 16), b3 = ubits(ub.y & 0xffff0000u);
                float g0 = ubits(gg.x << 16), g1 = ubits(gg.x & 0xffff0000u);
                float g2 = ubits(gg.y << 16), g3 = ubits(gg.y & 0xffff0000u);
                float sm = g0 * (a0 - b0) + g1 * (a1 - b1)
                         + g2 * (a2 - b2) + g3 * (a3 - b3);
                DPP_ADD_F(sm, 0x111);  // row_shr:1
                DPP_ADD_F(sm, 0x112);  // row_shr:2
                DPP_ADD_F(sm, 0x114);  // row_shr:4
                DPP_ADD_F(sm, 0x118);  // row_shr:8
                DPP_ADD_F(sm, 0x142);  // row_bcast:15 -> lane31 / lane63 hold sums
                if (l32 == 31) wt[p] = 1.0f / (1.0f + __expf(-sm));
            }
        }
        __syncthreads();   // S5: weights ready

        // ---- mix (in-thread) + fused pair exchange for next stage ----
        {
            const float w0 = wt[lane];
            if (u < NS - 1) {
                const bool isE = ((lane >> u) & 1) == 0;
                const float wk = isE ? w0 : 1.0f - w0;
#pragma unroll
                for (int j = 0; j < 16; ++j) {
                    float a = vlo[j], c = vhi[j];
                    float s    = a + c;
                    float keep = c + wk * (a - c);   // E: out_a ; O: out_b
                    float send = s - keep;           // E: out_b ; O: out_a
                    float ex   = xlane_u(send, u, lane);
                    vlo[j] = isE ? keep : ex;
                    vhi[j] = isE ? ex : keep;
                }
            } else {
                const float w1 = 1.0f - w0;
#pragma unroll
                for (int j = 0; j < 16; ++j) {
                    float a = vlo[j], c = vhi[j];
                    float oa = w0 * a + w1 * c;
                    vlo[j] = oa;
                    vhi[j] = a + c - oa;
                }
            }
        }
    }

    // ---- store v registers -> vdst (layout of final stage NS-1) ----
    {
        const int FU = NS - 1;
        int r0 = ((lane >> FU) << (FU + 1)) | (lane & ((1 << FU) - 1));
        int r1 = r0 + (1 << FU);
        int gp0 = base + (r0 >> 6) * h_off + (r0 & 63) * rstride;
        int gp1 = base + (r1 >> 6) * h_off + (r1 & 63) * rstride;
        float* p0 = vdst + (size_t)gp0 * 128 + w * 16;
        float* p1 = vdst + (size_t)gp1 * 128 + w * 16;
#pragma unroll
        for (int j = 0; j < 4; ++j) {
            float4 a; a.x = vlo[4*j]; a.y = vlo[4*j+1]; a.z = vlo[4*j+2]; a.w = vlo[4*j+3];
            float4 c; c.x = vhi[4*j]; c.y = vhi[4*j+1]; c.z = vhi[4*j+2]; c.w = vhi[4*j+3];
            ((float4*)p0)[j] = a;
            ((float4*)p1)[j] = c;
        }
    }
}

extern "C" void kernel_launch(void* const* d_in, const int* in_sizes, int n_in,
                              void* d_out, int out_size, void* d_ws, size_t ws_size,
                              hipStream_t stream) {
    const float* x   = (const float*)d_in[0];
    const float* qkw = (const float*)d_in[1];
    float* out = (float*)d_out;
    unsigned short* PT = (unsigned short*)d_ws;   // 13*16384 bf16 = 416 KB

    (void)hipFuncSetAttribute((const void*)prep_kernel,
                              hipFuncAttributeMaxDynamicSharedMemorySize, PREP_LDS);
    (void)hipFuncSetAttribute((const void*)butterfly_kernel<7>,
                              hipFuncAttributeMaxDynamicSharedMemorySize, LDS_MAIN);
    (void)hipFuncSetAttribute((const void*)butterfly_kernel<6>,
                              hipFuncAttributeMaxDynamicSharedMemorySize, LDS_MAIN);

    prep_kernel<<<13, 512, PREP_LDS, stream>>>(qkw, PT);

    // stages 0..6: contiguous 128-position blocks; v init = x
    butterfly_kernel<7><<<1024, 512, LDS_MAIN, stream>>>(
        x, x, out, PT, /*s0=*/0, /*base_mul=*/128, /*h_off=*/64, /*rstride=*/1);

    // stages 7..12: 2 lo x 64 hi (stride 128); in-place on d_out
    butterfly_kernel<6><<<1024, 512, LDS_MAIN, stream>>>(
        x, out, out, PT, /*s0=*/7, /*base_mul=*/2, /*h_off=*/1, /*rstride=*/128);
}